// Round 3
// baseline (111.974 us; speedup 1.0000x reference)
//
#include <hip/hip_runtime.h>
#include <hip/hip_bf16.h>

// GlobalEmbedder: packed-graph MHA (128 graphs x 32 nodes, D=128, H=4, K=32)
// k0: one-time prep:
//     blocks 0..63  : Wo [128][4096] fp32 -> WoT [4096][128] bf16 (transpose)
//     blocks 64..69 : Wq/Wk/Wv [128][128] fp32 -> WqkvT[3][128][128] bf16
//     blocks 70..133: nodes [4096][128] fp32 -> nodesBF bf16 (elementwise)
// k1: fused QKV+attention, block=(g,h) x 2 waves (16 rows each).
//     A-fragments loaded DIRECT from nodesBF (16B contiguous) - no staging,
//     one __syncthreads total (sK/sVT cross-wave). 1024 waves -> 4 waves/CU.
// k3: out = attout @ Wo + bo, LDS-staged 128x128 tiles (proven), float4 epilogue.

typedef __attribute__((ext_vector_type(4))) float f32x4;
typedef __attribute__((ext_vector_type(8))) short s16x8;
typedef __attribute__((ext_vector_type(4))) short s16x4;
typedef __attribute__((ext_vector_type(8))) __bf16 bf16x8;

static __device__ __forceinline__ short f2bf(float f) {
  union { float f; unsigned u; } v; v.f = f;
  unsigned r = v.u + 0x7fffu + ((v.u >> 16) & 1u);  // RNE
  return (short)(r >> 16);
}

static __device__ __forceinline__ f32x4 mfma16(s16x8 a, s16x8 b, f32x4 c) {
  return __builtin_amdgcn_mfma_f32_16x16x32_bf16(
      __builtin_bit_cast(bf16x8, a), __builtin_bit_cast(bf16x8, b), c, 0, 0, 0);
}

// ---------------------------------------------------------------- kernel 0
__global__ __launch_bounds__(256) void k0_prep(
    const float* __restrict__ nodes,
    const float* __restrict__ Wq, const float* __restrict__ Wk,
    const float* __restrict__ Wv, const float* __restrict__ Wo,
    unsigned short* __restrict__ WqkvT, unsigned short* __restrict__ WoT,
    unsigned short* __restrict__ nodesBF)
{
  const int b = blockIdx.x;
  const int t = threadIdx.x;

  if (b >= 70) {                       // ---- nodes fp32 -> bf16, 64 rows/block
    const int r0 = (b - 70) << 6;
    const float* src = nodes + r0 * 128;
    unsigned short* dst = nodesBF + r0 * 128;
    #pragma unroll
    for (int i = 0; i < 8; ++i) {
      int idx = (i * 256 + t) << 2;
      float4 v = *(const float4*)(src + idx);
      s16x4 p;
      p[0] = f2bf(v.x); p[1] = f2bf(v.y); p[2] = f2bf(v.z); p[3] = f2bf(v.w);
      *(s16x4*)(dst + idx) = p;
    }
    return;
  }

  // ---- [128][C] fp32 -> [C][128] bf16 transpose, 64-col stripes per block
  __shared__ alignas(16) short sT[64][136];   // [col][row]
  const float* in; unsigned short* out; int C; int n0;
  if (b < 64)      { in = Wo; out = WoT;           C = 4096; n0 = b << 6; }
  else if (b < 66) { in = Wq; out = WqkvT;         C = 128;  n0 = (b - 64) << 6; }
  else if (b < 68) { in = Wk; out = WqkvT + 16384; C = 128;  n0 = (b - 66) << 6; }
  else             { in = Wv; out = WqkvT + 32768; C = 128;  n0 = (b - 68) << 6; }
  const int rr = t >> 4;          // 0..15
  const int c4 = (t & 15) << 2;   // 0..60
  #pragma unroll
  for (int i = 0; i < 8; ++i) {
    int r = i * 16 + rr;
    float4 v = *(const float4*)(in + r * C + n0 + c4);   // coalesced
    sT[c4 + 0][r] = f2bf(v.x);
    sT[c4 + 1][r] = f2bf(v.y);
    sT[c4 + 2][r] = f2bf(v.z);
    sT[c4 + 3][r] = f2bf(v.w);
  }
  __syncthreads();
  const int c  = t >> 2;          // 0..63
  const int k0 = (t & 3) << 5;    // 0,32,64,96
  #pragma unroll
  for (int j = 0; j < 4; ++j)     // coalesced 16B writes
    *(s16x8*)&out[(n0 + c) * 128 + k0 + j * 8] = *(const s16x8*)&sT[c][k0 + j * 8];
}

// ---------------------------------------------------------------- kernel 1
// grid (128 graphs, 4 heads), 128 threads = 2 waves; wave w owns rows w*16..+15.
__global__ __launch_bounds__(128) void k1_qkv_attn(
    const unsigned short* __restrict__ nodesBF,  // [4096][128] bf16
    const unsigned short* __restrict__ WqkvT,    // [3][n=h*32+c][d]
    const float* __restrict__ bq, const float* __restrict__ bk,
    const float* __restrict__ bv,
    unsigned short* __restrict__ attout)
{
  const int g = blockIdx.x;
  const int h = blockIdx.y;
  const int t = threadIdx.x;
  const int wv   = t >> 6;        // wave id: 0,1
  const int lane = t & 63;
  const int l15  = lane & 15;
  const int qd   = lane >> 4;
  const int mrow = wv << 4;       // this wave's row base (0 or 16)

  __shared__ alignas(16) short sQ[32][40];    // q[m][c] (pre-scaled)
  __shared__ alignas(16) short sK[32][40];    // k[m'][c]   (cross-wave)
  __shared__ alignas(16) short sVT[32][40];   // v^T[n][m]  (cross-wave)
  __shared__ alignas(16) short sP[32][40];    // probs [m][m'] (wave-private rows)

  // ---- A-fragments direct from global (16B contiguous, L2-hot bf16 nodes)
  s16x8 afrag[4];
  const unsigned short* nb = nodesBF + (g * 32 + mrow + l15) * 128 + qd * 8;
  #pragma unroll
  for (int kk = 0; kk < 4; ++kk) afrag[kk] = *(const s16x8*)(nb + kk * 32);

  // ---- hoist ALL B-fragments (3 proj x 4 kk x 2 nt = 24 x 16B, L2-hot)
  s16x8 bfr[3][4][2];
  #pragma unroll
  for (int m3 = 0; m3 < 3; ++m3) {
    const unsigned short* WT = WqkvT + m3 * 16384 + (h * 32 + l15) * 128 + qd * 8;
    #pragma unroll
    for (int kk = 0; kk < 4; ++kk)
      #pragma unroll
      for (int nt = 0; nt < 2; ++nt)
        bfr[m3][kk][nt] = *(const s16x8*)(WT + nt * 16 * 128 + kk * 32);
  }
  const float* Bm[3] = {bq, bk, bv};

  // ---- QKV projections (M=16 per wave, N=32, K=128)
  #pragma unroll
  for (int m3 = 0; m3 < 3; ++m3) {
    f32x4 acc[2];
    f32x4 zero = {0.f, 0.f, 0.f, 0.f};
    acc[0] = zero; acc[1] = zero;
    #pragma unroll
    for (int kk = 0; kk < 4; ++kk)
      #pragma unroll
      for (int nt = 0; nt < 2; ++nt)
        acc[nt] = mfma16(afrag[kk], bfr[m3][kk][nt], acc[nt]);
    float b0 = Bm[m3][h * 32 + l15];
    float b1 = Bm[m3][h * 32 + 16 + l15];
    #pragma unroll
    for (int nt = 0; nt < 2; ++nt) {
      float bb = nt ? b1 : b0;
      #pragma unroll
      for (int r = 0; r < 4; ++r) {
        int m = mrow + qd * 4 + r;          // C/D: row=quad*4+reg
        int c = nt * 16 + l15;              //      col=lane&15
        float val = acc[nt][r] + bb;
        if (m3 == 0)      sQ[m][c]  = f2bf(val * 0.17677669529663687f); // 1/sqrt(32)
        else if (m3 == 1) sK[m][c]  = f2bf(val);
        else              sVT[c][m] = f2bf(val);   // transposed for PV B-operand
      }
    }
  }
  __syncthreads();   // sK/sVT cross-wave

  // ---- scores = q @ k^T  (M=16, N=32, K=32 -> 2 MFMA per wave)
  s16x8 qf = *(const s16x8*)&sQ[mrow + l15][qd * 8];
  s16x8 kf[2];
  #pragma unroll
  for (int nt = 0; nt < 2; ++nt) kf[nt] = *(const s16x8*)&sK[nt * 16 + l15][qd * 8];
  f32x4 sacc[2];
  {
    f32x4 zero = {0.f, 0.f, 0.f, 0.f};
    sacc[0] = mfma16(qf, kf[0], zero);
    sacc[1] = mfma16(qf, kf[1], zero);
  }

  // ---- softmax over 32 cols (rows mrow..mrow+15, 16-lane groups)
  #pragma unroll
  for (int r = 0; r < 4; ++r) {
    float a0 = sacc[0][r], a1 = sacc[1][r];
    float mx = fmaxf(a0, a1);
    mx = fmaxf(mx, __shfl_xor(mx, 1, 64));
    mx = fmaxf(mx, __shfl_xor(mx, 2, 64));
    mx = fmaxf(mx, __shfl_xor(mx, 4, 64));
    mx = fmaxf(mx, __shfl_xor(mx, 8, 64));
    float e0 = __expf(a0 - mx), e1 = __expf(a1 - mx);
    float s = e0 + e1;
    s += __shfl_xor(s, 1, 64);
    s += __shfl_xor(s, 2, 64);
    s += __shfl_xor(s, 4, 64);
    s += __shfl_xor(s, 8, 64);
    float inv = 1.0f / s;
    int m = mrow + qd * 4 + r;
    sP[m][l15]      = f2bf(e0 * inv);
    sP[m][16 + l15] = f2bf(e1 * inv);
  }
  // sP rows are wave-private: no barrier needed (compiler inserts lgkmcnt waits)

  // ---- out = P @ v  (2 MFMA per wave), write attout bf16
  s16x8 pf = *(const s16x8*)&sP[mrow + l15][qd * 8];
  s16x8 vf[2];
  #pragma unroll
  for (int nt = 0; nt < 2; ++nt) vf[nt] = *(const s16x8*)&sVT[nt * 16 + l15][qd * 8];
  f32x4 oacc[2];
  {
    f32x4 zero = {0.f, 0.f, 0.f, 0.f};
    oacc[0] = mfma16(pf, vf[0], zero);
    oacc[1] = mfma16(pf, vf[1], zero);
  }
  unsigned short* ao = attout + (g * 32 + mrow) * 128 + h * 32;
  #pragma unroll
  for (int nt = 0; nt < 2; ++nt)
    #pragma unroll
    for (int r = 0; r < 4; ++r)
      ao[(qd * 4 + r) * 128 + nt * 16 + l15] = (unsigned short)f2bf(oacc[nt][r]);
}

// ---------------------------------------------------------------- kernel 3
// C[4096][4096] = attout[4096][128] @ Wo[128][4096] + bo. 128x128 tiles, K=128 whole.
// LDS-staged. Operand-swapped MFMA epilogue: D[n][m] -> each lane's 4 acc regs
// = 4 consecutive output columns -> float4 cached stores.
__global__ __launch_bounds__(256) void k3_gemm(
    const unsigned short* __restrict__ A,   // attout bf16 [4096][128]
    const unsigned short* __restrict__ BT,  // WoT bf16 [4096 n][128 k]
    const float* __restrict__ bo,
    float* __restrict__ C)
{
  __shared__ alignas(16) short sA[128][136];
  __shared__ alignas(16) short sB[128][136];
  const int t  = threadIdx.x;
  const int m0 = blockIdx.y << 7;
  const int n0 = blockIdx.x << 7;

  #pragma unroll
  for (int i = 0; i < 8; ++i) {
    int id  = i * 256 + t;
    int row = id >> 4;
    int ch  = (id & 15) << 3;
    *(s16x8*)&sA[row][ch] = *(const s16x8*)(A  + (m0 + row) * 128 + ch);
    *(s16x8*)&sB[row][ch] = *(const s16x8*)(BT + (n0 + row) * 128 + ch);
  }
  __syncthreads();

  const int w    = t >> 6;
  const int lane = t & 63;
  const int l15  = lane & 15;
  const int qd   = lane >> 4;
  const int wm   = (w >> 1) << 6;   // 0 or 64
  const int wn   = (w & 1) << 6;    // 0 or 64

  f32x4 acc[4][4];   // acc[j][i]: j = n-tile, i = m-tile (operand-swapped)
  {
    f32x4 zero = {0.f, 0.f, 0.f, 0.f};
    #pragma unroll
    for (int j = 0; j < 4; ++j)
      #pragma unroll
      for (int i = 0; i < 4; ++i) acc[j][i] = zero;
  }

  #pragma unroll
  for (int kk = 0; kk < 4; ++kk) {
    s16x8 af[4], bf[4];
    #pragma unroll
    for (int i = 0; i < 4; ++i)
      af[i] = *(const s16x8*)&sA[wm + i * 16 + l15][kk * 32 + qd * 8];
    #pragma unroll
    for (int j = 0; j < 4; ++j)
      bf[j] = *(const s16x8*)&sB[wn + j * 16 + l15][kk * 32 + qd * 8];
    #pragma unroll
    for (int j = 0; j < 4; ++j)
      #pragma unroll
      for (int i = 0; i < 4; ++i)
        acc[j][i] = mfma16(bf[j], af[i], acc[j][i]);   // D[n][m]
  }

  // bias: lane's 4 regs are 4 consecutive columns n0+wn+j*16+qd*4 .. +3
  f32x4 bv4[4];
  #pragma unroll
  for (int j = 0; j < 4; ++j)
    bv4[j] = *(const f32x4*)&bo[n0 + wn + j * 16 + qd * 4];

  #pragma unroll
  for (int i = 0; i < 4; ++i) {
    float* crow = C + (m0 + wm + i * 16 + l15) * 4096 + n0 + wn + qd * 4;
    #pragma unroll
    for (int j = 0; j < 4; ++j) {
      f32x4 v = acc[j][i] + bv4[j];
      *(f32x4*)(crow + j * 16) = v;
    }
  }
}

// ---------------------------------------------------------------- launch
extern "C" void kernel_launch(void* const* d_in, const int* in_sizes, int n_in,
                              void* d_out, int out_size, void* d_ws, size_t ws_size,
                              hipStream_t stream) {
  const float* nodes = (const float*)d_in[0];
  // d_in[1] = n_node (always 32 per graph) — segmentation hard-coded
  const float* Wq = (const float*)d_in[2];
  const float* bq = (const float*)d_in[3];
  const float* Wk = (const float*)d_in[4];
  const float* bk = (const float*)d_in[5];
  const float* Wv = (const float*)d_in[6];
  const float* bv = (const float*)d_in[7];
  const float* Wo = (const float*)d_in[8];
  const float* bo = (const float*)d_in[9];
  float* out = (float*)d_out;

  unsigned short* attout  = (unsigned short*)d_ws;         // 4096*128 bf16
  unsigned short* WoT     = attout + 4096 * 128;           // 4096*128 bf16
  unsigned short* WqkvT   = WoT + 4096 * 128;              // 3*128*128 bf16
  unsigned short* nodesBF = WqkvT + 3 * 128 * 128;         // 4096*128 bf16

  k0_prep<<<134, 256, 0, stream>>>(nodes, Wq, Wk, Wv, Wo, WqkvT, WoT, nodesBF);
  k1_qkv_attn<<<dim3(128, 4), 128, 0, stream>>>(nodesBF, WqkvT, bq, bk, bv, attout);
  k3_gemm<<<dim3(32, 32), 256, 0, stream>>>(attout, WoT, bo, out);
}